// Round 1
// baseline (150.029 us; speedup 1.0000x reference)
//
#include <hip/hip_runtime.h>

#define NNODE 2048
#define DD    512
#define HHID  256
#define LLAT  16
#define H2    32   // 2L

typedef __attribute__((ext_vector_type(8))) short  short8;
typedef __attribute__((ext_vector_type(4))) float  f32x4;

__device__ __forceinline__ unsigned short f2bf(float x) {
    unsigned int u = __float_as_uint(x);
    unsigned int r = (u + 0x7fffu + ((u >> 16) & 1u)) >> 16;  // RNE
    return (unsigned short)r;
}
__device__ __forceinline__ float bf2f(unsigned short u) {
    return __uint_as_float(((unsigned int)u) << 16);
}

// ---------------- K1: fused {A->bf16 convert} || {XWt = bf16(W1 @ X^T)} ----------
// grid 256: blocks 0..127 = GEMM (4 h-tiles x 32 n-tiles), 128..255 = A convert
__global__ __launch_bounds__(256) void k1_cvt_xw(const float* __restrict__ A,
                                                 const float* __restrict__ X,
                                                 const float* __restrict__ W1,
                                                 unsigned short* __restrict__ Abf,
                                                 unsigned short* __restrict__ XWt) {
    const int tid = threadIdx.x;
    if (blockIdx.x >= 128) {
        // convert A: 4.2M floats = 1048576 float4, 128 blocks x 256 thr, 32 iters
        for (int v = (blockIdx.x - 128) * 256 + tid; v < 1048576; v += 32768) {
            float4 f = ((const float4*)A)[v];
            short4 h;
            h.x = (short)f2bf(f.x); h.y = (short)f2bf(f.y);
            h.z = (short)f2bf(f.z); h.w = (short)f2bf(f.w);
            ((short4*)Abf)[v] = h;
        }
        return;
    }
    __shared__ __align__(16) unsigned short Ab[64][40];
    __shared__ __align__(16) unsigned short Bb[64][40];
    const int h0 = (blockIdx.x & 3) * 64;
    const int n0 = (blockIdx.x >> 2) * 64;
    const int lane = tid & 63, wave = tid >> 6;
    const int wm = wave >> 1, wn = wave & 1;
    const int lm = lane & 15, lk = (lane >> 4) * 8;
    const int sr = tid >> 2, sc = (tid & 3) * 8;
    f32x4 acc[2][2] = {};
    for (int it = 0; it < 16; ++it) {
        int kk = it * 32;
        {
            const float* ap = W1 + (size_t)(h0 + sr) * DD + kk + sc;
            float4 f0 = *(const float4*)ap;
            float4 f1 = *(const float4*)(ap + 4);
            short8 h;
            h[0] = (short)f2bf(f0.x); h[1] = (short)f2bf(f0.y);
            h[2] = (short)f2bf(f0.z); h[3] = (short)f2bf(f0.w);
            h[4] = (short)f2bf(f1.x); h[5] = (short)f2bf(f1.y);
            h[6] = (short)f2bf(f1.z); h[7] = (short)f2bf(f1.w);
            *(short8*)&Ab[sr][sc] = h;
            const float* bp = X + (size_t)(n0 + sr) * DD + kk + sc;
            float4 g0 = *(const float4*)bp;
            float4 g1 = *(const float4*)(bp + 4);
            short8 g;
            g[0] = (short)f2bf(g0.x); g[1] = (short)f2bf(g0.y);
            g[2] = (short)f2bf(g0.z); g[3] = (short)f2bf(g0.w);
            g[4] = (short)f2bf(g1.x); g[5] = (short)f2bf(g1.y);
            g[6] = (short)f2bf(g1.z); g[7] = (short)f2bf(g1.w);
            *(short8*)&Bb[sr][sc] = g;
        }
        __syncthreads();
        short8 a0 = *(const short8*)&Ab[wm * 32 + lm][lk];
        short8 a1 = *(const short8*)&Ab[wm * 32 + 16 + lm][lk];
        short8 b0 = *(const short8*)&Bb[wn * 32 + lm][lk];
        short8 b1 = *(const short8*)&Bb[wn * 32 + 16 + lm][lk];
        acc[0][0] = __builtin_amdgcn_mfma_f32_16x16x32_bf16(a0, b0, acc[0][0], 0, 0, 0);
        acc[0][1] = __builtin_amdgcn_mfma_f32_16x16x32_bf16(a0, b1, acc[0][1], 0, 0, 0);
        acc[1][0] = __builtin_amdgcn_mfma_f32_16x16x32_bf16(a1, b0, acc[1][0], 0, 0, 0);
        acc[1][1] = __builtin_amdgcn_mfma_f32_16x16x32_bf16(a1, b1, acc[1][1], 0, 0, 0);
        __syncthreads();
    }
    #pragma unroll
    for (int mi = 0; mi < 2; ++mi)
        #pragma unroll
        for (int ni = 0; ni < 2; ++ni)
            #pragma unroll
            for (int r = 0; r < 4; ++r) {
                int row = h0 + wm * 32 + mi * 16 + (lane >> 4) * 4 + r;
                int col = n0 + wn * 32 + ni * 16 + lm;
                XWt[(size_t)row * NNODE + col] = f2bf(acc[mi][ni][r]);
            }
}

// ---------------- K2: Hbf = bf16(leaky(A @ XW + b1)), full-K, reg-prefetch -------
// grid (32 m-tiles of 64, 8 h-tiles of 32); BK=64, 32 iters
__global__ __launch_bounds__(256) void k2_h(const unsigned short* __restrict__ Abf,
                                            const unsigned short* __restrict__ XWt,
                                            const float* __restrict__ bias1,
                                            unsigned short* __restrict__ Hbf) {
    __shared__ __align__(16) unsigned short Ab[64][72];
    __shared__ __align__(16) unsigned short Bb[32][72];
    const int tid = threadIdx.x;
    const int m0 = blockIdx.x * 64;
    const int h0 = blockIdx.y * 32;
    const int lane = tid & 63, wave = tid >> 6;
    const int lm = lane & 15, lk = (lane >> 4) * 8;
    const int sr = tid >> 2, sc = (tid & 3) * 16;   // A: 64 rows x 64 k, 2 uint4/thr
    const int br = tid >> 3, bc = (tid & 7) * 8;    // B: 32 rows x 64 k, 1 uint4/thr
    f32x4 acc[2] = {};
    const unsigned short* aA = Abf + (size_t)(m0 + sr) * NNODE + sc;
    const unsigned short* aB = XWt + (size_t)(h0 + br) * NNODE + bc;
    uint4 ra0 = *(const uint4*)(aA);
    uint4 ra1 = *(const uint4*)(aA + 8);
    uint4 rb  = *(const uint4*)(aB);
    for (int it = 0; it < 32; ++it) {
        *(uint4*)&Ab[sr][sc]     = ra0;
        *(uint4*)&Ab[sr][sc + 8] = ra1;
        *(uint4*)&Bb[br][bc]     = rb;
        __syncthreads();
        if (it < 31) {
            int kk = (it + 1) * 64;
            ra0 = *(const uint4*)(aA + kk);
            ra1 = *(const uint4*)(aA + kk + 8);
            rb  = *(const uint4*)(aB + kk);
        }
        #pragma unroll
        for (int ko = 0; ko < 2; ++ko) {
            short8 a  = *(const short8*)&Ab[wave * 16 + lm][ko * 32 + lk];
            short8 b0 = *(const short8*)&Bb[lm][ko * 32 + lk];
            short8 b1 = *(const short8*)&Bb[16 + lm][ko * 32 + lk];
            acc[0] = __builtin_amdgcn_mfma_f32_16x16x32_bf16(a, b0, acc[0], 0, 0, 0);
            acc[1] = __builtin_amdgcn_mfma_f32_16x16x32_bf16(a, b1, acc[1], 0, 0, 0);
        }
        __syncthreads();
    }
    const int q = lane >> 4;
    #pragma unroll
    for (int ni = 0; ni < 2; ++ni) {
        int col = h0 + ni * 16 + lm;
        float bb = bias1[col];
        #pragma unroll
        for (int r = 0; r < 4; ++r) {
            int row = m0 + wave * 16 + q * 4 + r;
            float s = acc[ni][r] + bb;
            s = fmaxf(s, 0.01f * s);
            Hbf[(size_t)row * HHID + col] = f2bf(s);
        }
    }
}

// ---------------- T3: Gt[j][n] = bf16( sum_d Hbf[n][d] * Wcat[j][d] ) ------------
__global__ __launch_bounds__(256) void t3_g(const unsigned short* __restrict__ Hbf,
                                            const float* __restrict__ Wmu,
                                            const float* __restrict__ Wlv,
                                            unsigned short* __restrict__ Gt) {
    __shared__ float Hs[8][260];
    __shared__ float Ws[32][260];
    const int tid = threadIdx.x;
    const int n0 = blockIdx.x * 8;
    #pragma unroll
    for (int s = 0; s < 8; ++s) {
        int idx = tid + s * 256;            // float4 units, 0..2047
        int row = idx >> 6, c = (idx & 63) * 4;
        const float* src = (row < 16) ? (Wmu + (size_t)row * HHID)
                                      : (Wlv + (size_t)(row - 16) * HHID);
        *(float4*)&Ws[row][c] = *(const float4*)(src + c);
    }
    {
        int r = tid >> 5, seg = tid & 31;
        int d = seg * 8;
        ushort4 u0 = *(const ushort4*)(Hbf + (size_t)(n0 + r) * HHID + d);
        ushort4 u1 = *(const ushort4*)(Hbf + (size_t)(n0 + r) * HHID + d + 4);
        Hs[r][d + 0] = bf2f(u0.x); Hs[r][d + 1] = bf2f(u0.y);
        Hs[r][d + 2] = bf2f(u0.z); Hs[r][d + 3] = bf2f(u0.w);
        Hs[r][d + 4] = bf2f(u1.x); Hs[r][d + 5] = bf2f(u1.y);
        Hs[r][d + 6] = bf2f(u1.z); Hs[r][d + 7] = bf2f(u1.w);
    }
    __syncthreads();
    const int r = tid >> 5, j = tid & 31;
    float acc = 0.f;
    #pragma unroll 8
    for (int d4 = 0; d4 < 64; ++d4) {
        float4 a = *(const float4*)&Hs[r][d4 * 4];
        float4 b = *(const float4*)&Ws[j][d4 * 4];
        acc += a.x * b.x + a.y * b.y + a.z * b.z + a.w * b.w;
    }
    Gt[(size_t)j * NNODE + n0 + r] = f2bf(acc);
}

// ---------------- K4: Mp[s][m][c] = partial A @ G  (MFMA, splitK=8, prefetch) ----
__global__ __launch_bounds__(256) void k4_m(const unsigned short* __restrict__ Abf,
                                            const unsigned short* __restrict__ Gt,
                                            float* __restrict__ Mp) {
    __shared__ __align__(16) unsigned short Ab[64][40];
    __shared__ __align__(16) unsigned short Bb[32][40];
    const int tid = threadIdx.x;
    const int m0 = blockIdx.x * 64;
    const int ks = blockIdx.y;          // 0..7, K chunk of 256
    const int lane = tid & 63, wave = tid >> 6;
    const int lm = lane & 15, lk = (lane >> 4) * 8;
    const int sr = tid >> 2, sc = (tid & 3) * 8;
    f32x4 acc[2] = {};
    const int kbase = ks * 256;
    const unsigned short* aA = Abf + (size_t)(m0 + sr) * NNODE + kbase + sc;
    const unsigned short* aB = Gt;
    uint4 ra = *(const uint4*)aA;
    uint4 rb = {};
    if (tid < 128) {
        aB = Gt + (size_t)(tid >> 2) * NNODE + kbase + (tid & 3) * 8;
        rb = *(const uint4*)aB;
    }
    for (int it = 0; it < 8; ++it) {
        *(uint4*)&Ab[sr][sc] = ra;
        if (tid < 128) *(uint4*)&Bb[tid >> 2][(tid & 3) * 8] = rb;
        __syncthreads();
        if (it < 7) {
            ra = *(const uint4*)(aA + (it + 1) * 32);
            if (tid < 128) rb = *(const uint4*)(aB + (it + 1) * 32);
        }
        short8 a  = *(const short8*)&Ab[wave * 16 + lm][lk];
        short8 b0 = *(const short8*)&Bb[lm][lk];
        short8 b1 = *(const short8*)&Bb[16 + lm][lk];
        acc[0] = __builtin_amdgcn_mfma_f32_16x16x32_bf16(a, b0, acc[0], 0, 0, 0);
        acc[1] = __builtin_amdgcn_mfma_f32_16x16x32_bf16(a, b1, acc[1], 0, 0, 0);
        __syncthreads();
    }
    float* outp = Mp + (size_t)ks * 65536;
    #pragma unroll
    for (int ni = 0; ni < 2; ++ni)
        #pragma unroll
        for (int r = 0; r < 4; ++r) {
            int row = m0 + wave * 16 + (lane >> 4) * 4 + r;
            int col = ni * 16 + lm;
            outp[(size_t)row * H2 + col] = acc[ni][r];
        }
}

// ---------------- T5: reduce Mp; mu/logvar; Z; P', Q, and WP/WQ ------------------
__global__ __launch_bounds__(256) void t5_z(const float* __restrict__ Mp,
                                            const float* __restrict__ bmu,
                                            const float* __restrict__ blv,
                                            const float* __restrict__ eps,
                                            const float* __restrict__ Wd1,
                                            const float* __restrict__ bd1,
                                            const float* __restrict__ Wd2,
                                            float* __restrict__ out_mu,
                                            float* __restrict__ out_lv,
                                            float* __restrict__ Pp,
                                            float* __restrict__ Qq,
                                            float* __restrict__ WP,
                                            float* __restrict__ WQ) {
    __shared__ float Zs[16][16];
    __shared__ float Psh[16][32];
    __shared__ float Qsh[16][32];
    const int tid = threadIdx.x;
    const int n0 = blockIdx.x * 16;
    {
        int nl = tid >> 4, l = tid & 15;
        int n = n0 + nl;
        float m = bmu[l], lv = blv[l];
        #pragma unroll
        for (int s = 0; s < 8; ++s) {
            m  += Mp[(size_t)s * 65536 + (size_t)n * H2 + l];
            lv += Mp[(size_t)s * 65536 + (size_t)n * H2 + 16 + l];
        }
        out_mu[(size_t)n * LLAT + l] = m;
        out_lv[(size_t)n * LLAT + l] = lv;
        Zs[nl][l] = m + eps[(size_t)n * LLAT + l] * __expf(0.5f * lv);
    }
    __syncthreads();
    #pragma unroll
    for (int p = 0; p < 2; ++p) {
        int idx = tid + p * 256;            // 0..511
        int nl = idx >> 5, o = idx & 31;
        int n = n0 + nl;
        float ap = bd1[o], aq = 0.f;
        #pragma unroll
        for (int l = 0; l < 16; ++l) {
            float z = Zs[nl][l];
            ap = fmaf(z, Wd1[o * H2 + l],      ap);
            aq = fmaf(z, Wd1[o * H2 + 16 + l], aq);
        }
        Pp[(size_t)n * H2 + o] = ap;
        Qq[(size_t)n * H2 + o] = aq;
        Psh[nl][o] = ap;
        Qsh[nl][o] = aq;
    }
    __syncthreads();
    if (tid < 32) {
        int nl = tid & 15, sel = tid >> 4;
        float a = 0.f;
        if (sel == 0) {
            #pragma unroll
            for (int o = 0; o < 32; ++o) a = fmaf(Wd2[o], Psh[nl][o], a);
            WP[n0 + nl] = a;
        } else {
            #pragma unroll
            for (int o = 0; o < 32; ++o) a = fmaf(Wd2[o], Qsh[nl][o], a);
            WQ[n0 + nl] = a;
        }
    }
}

// ---------------- T6: decoder via leaky(x)=0.505x+0.495|x| decomposition ---------
__global__ __launch_bounds__(256) void t6_dec(const float* __restrict__ Pp,
                                              const float* __restrict__ Qq,
                                              const float* __restrict__ WP,
                                              const float* __restrict__ WQ,
                                              const float* __restrict__ Wd2,
                                              const float* __restrict__ bd2,
                                              float* __restrict__ Apred) {
    __shared__ float Qt[32][68];   // transposed Q tile, padded
    __shared__ float Ws2[32];
    __shared__ float WQs[64];
    const int tid = threadIdx.x;
    const int j0 = blockIdx.x * 64, i0 = blockIdx.y * 16;
    #pragma unroll
    for (int s = 0; s < 8; ++s) {
        int idx = tid + s * 256;            // 0..2047
        int j = idx >> 5, o = idx & 31;
        Qt[o][j] = Qq[(size_t)(j0 + j) * H2 + o];
    }
    if (tid < 32) Ws2[tid] = Wd2[tid];
    if (tid >= 64 && tid < 128) WQs[tid - 64] = WQ[j0 + tid - 64];
    const int i = i0 + (tid >> 4);
    const int jq = tid & 15;
    float p[32];
    const float4* P4 = (const float4*)(Pp + (size_t)i * H2);
    #pragma unroll
    for (int c = 0; c < 8; ++c) {
        float4 v = P4[c];
        p[c * 4] = v.x; p[c * 4 + 1] = v.y; p[c * 4 + 2] = v.z; p[c * 4 + 3] = v.w;
    }
    const float WPi = WP[i];
    __syncthreads();
    f32x4 acc = {0.f, 0.f, 0.f, 0.f};   // sum_o w*|P+Q|
    #pragma unroll
    for (int o = 0; o < 32; ++o) {
        float4 q = *(const float4*)&Qt[o][jq * 4];
        float w = Ws2[o], po = p[o];
        acc[0] = fmaf(w, fabsf(po + q.x), acc[0]);
        acc[1] = fmaf(w, fabsf(po + q.y), acc[1]);
        acc[2] = fmaf(w, fabsf(po + q.z), acc[2]);
        acc[3] = fmaf(w, fabsf(po + q.w), acc[3]);
    }
    float4 wq = *(const float4*)&WQs[jq * 4];
    const float base = fmaf(0.505f, WPi, bd2[0]);
    float4 r;
    float l0 = fmaf(0.505f, wq.x, fmaf(0.495f, acc[0], base));
    float l1 = fmaf(0.505f, wq.y, fmaf(0.495f, acc[1], base));
    float l2 = fmaf(0.505f, wq.z, fmaf(0.495f, acc[2], base));
    float l3 = fmaf(0.505f, wq.w, fmaf(0.495f, acc[3], base));
    r.x = 1.f / (1.f + __expf(-l0));
    r.y = 1.f / (1.f + __expf(-l1));
    r.z = 1.f / (1.f + __expf(-l2));
    r.w = 1.f / (1.f + __expf(-l3));
    *(float4*)(Apred + (size_t)i * NNODE + j0 + jq * 4) = r;
}

extern "C" void kernel_launch(void* const* d_in, const int* in_sizes, int n_in,
                              void* d_out, int out_size, void* d_ws, size_t ws_size,
                              hipStream_t stream) {
    const float* A   = (const float*)d_in[0];
    const float* X   = (const float*)d_in[1];
    const float* eps = (const float*)d_in[2];
    const float* W1  = (const float*)d_in[3];
    const float* b1  = (const float*)d_in[4];
    const float* Wmu = (const float*)d_in[5];
    const float* bmu = (const float*)d_in[6];
    const float* Wlv = (const float*)d_in[7];
    const float* blv = (const float*)d_in[8];
    const float* Wd1 = (const float*)d_in[9];
    const float* bd1 = (const float*)d_in[10];
    const float* Wd2 = (const float*)d_in[11];
    const float* bd2 = (const float*)d_in[12];
    float* out = (float*)d_out;
    char* ws = (char*)d_ws;

    // workspace carve (~13.3 MB), all buffers fully overwritten each call
    unsigned short* Abf = (unsigned short*)(ws);                //  8,388,608
    unsigned short* XWt = (unsigned short*)(ws + 8388608);      //  1,048,576
    unsigned short* Hbf = (unsigned short*)(ws + 9437184);      //  1,048,576
    unsigned short* Gt  = (unsigned short*)(ws + 10485760);     //    131,072
    float*          Mp  = (float*)(ws + 10616832);              //  2,097,152 (8 x 256KB)
    float*          Pp  = (float*)(ws + 12713984);              //    262,144
    float*          Qq  = (float*)(ws + 12976128);              //    262,144
    float*          WP  = (float*)(ws + 13238272);              //      8,192
    float*          WQ  = (float*)(ws + 13246464);              //      8,192

    float* out_mu = out + (size_t)NNODE * NNODE;
    float* out_lv = out_mu + NNODE * LLAT;

    k1_cvt_xw<<<256,           256, 0, stream>>>(A, X, W1, Abf, XWt);
    k2_h     <<<dim3(32, 8),   256, 0, stream>>>(Abf, XWt, b1, Hbf);
    t3_g     <<<256,           256, 0, stream>>>(Hbf, Wmu, Wlv, Gt);
    k4_m     <<<dim3(32, 8),   256, 0, stream>>>(Abf, Gt, Mp);
    t5_z     <<<128,           256, 0, stream>>>(Mp, bmu, blv, eps, Wd1, bd1, Wd2,
                                                 out_mu, out_lv, Pp, Qq, WP, WQ);
    t6_dec   <<<dim3(32, 128), 256, 0, stream>>>(Pp, Qq, WP, WQ, Wd2, bd2, out);
}